// Round 5
// baseline (243.945 us; speedup 1.0000x reference)
//
#include <hip/hip_runtime.h>

// Dense image warp (bilinear), B=8 H=256 W=256 C=64, fp32.
// 16 threads per pixel (one float4 quad each), two adjacent pixels per thread.
// R5 (= R4 fixed): XCD band swizzle (XCD k handles batch k => gather halo in
// its private 4 MiB L2), nontemporal stores (don't write-allocate out),
// nontemporal flow load. NT builtins need native Clang vectors, not float4.

typedef float nvec4 __attribute__((ext_vector_type(4)));

__device__ __forceinline__ float4 bilerp4(float4 a, float4 b, float4 c, float4 d,
                                          float ax, float ay) {
    float4 r;
    float top, bot;
    top = fmaf(ax, b.x - a.x, a.x);
    bot = fmaf(ax, d.x - c.x, c.x);
    r.x = fmaf(ay, bot - top, top);
    top = fmaf(ax, b.y - a.y, a.y);
    bot = fmaf(ax, d.y - c.y, c.y);
    r.y = fmaf(ay, bot - top, top);
    top = fmaf(ax, b.z - a.z, a.z);
    bot = fmaf(ax, d.z - c.z, c.z);
    r.z = fmaf(ay, bot - top, top);
    top = fmaf(ax, b.w - a.w, a.w);
    bot = fmaf(ax, d.w - c.w, c.w);
    r.w = fmaf(ay, bot - top, top);
    return r;
}

__global__ __launch_bounds__(256) void warp_bilinear_kernel(
    const float* __restrict__ image,
    const float* __restrict__ flow,
    float* __restrict__ out)
{
    constexpr int H = 256, W = 256;
    constexpr unsigned QUADS = 16;        // float4 per pixel (C=64)
    constexpr unsigned ROWQ = W * QUADS;  // float4 per image row

    // Band swizzle: default dispatch round-robins consecutive blocks over the
    // 8 XCDs (xcd = bid % 8). Remap so XCD k gets the contiguous block range
    // [k*nb/8, (k+1)*nb/8) => XCD k processes exactly batch image k, swept
    // row-sequentially. Gather halo (~10 rows, ~650 KB) stays in its L2.
    const int bid = (int)blockIdx.x;
    const int nb8 = (int)gridDim.x >> 3;          // 2048
    const int sbid = (bid & 7) * nb8 + (bid >> 3);

    const int gid = sbid * (int)blockDim.x + (int)threadIdx.x;
    const int i = gid >> 4;   // pixel-pair index
    const int t = gid & 15;   // quad within pixel
    const int p0 = i * 2;
    const int p1 = p0 + 1;

    // flow for both pixels in one 16 B nt load: {fy0, fx0, fy1, fx1}
    const nvec4 fl = __builtin_nontemporal_load(((const nvec4*)flow) + i);

    const int x0 = p0 & (W - 1), y0 = (p0 >> 8) & (H - 1), b0 = p0 >> 16;
    const int x1 = p1 & (W - 1), y1 = (p1 >> 8) & (H - 1), b1 = p1 >> 16;

    // query = grid - flow; tfa semantics: floor clamped [0,size-2], alpha [0,1]
    const float qy0 = (float)y0 - fl.x, qx0 = (float)x0 - fl.y;
    const float qy1 = (float)y1 - fl.z, qx1 = (float)x1 - fl.w;

    const float fy0 = fminf(fmaxf(floorf(qy0), 0.0f), (float)(H - 2));
    const float fx0 = fminf(fmaxf(floorf(qx0), 0.0f), (float)(W - 2));
    const float fy1 = fminf(fmaxf(floorf(qy1), 0.0f), (float)(H - 2));
    const float fx1 = fminf(fmaxf(floorf(qx1), 0.0f), (float)(W - 2));
    const float ay0 = fminf(fmaxf(qy0 - fy0, 0.0f), 1.0f);
    const float ax0 = fminf(fmaxf(qx0 - fx0, 0.0f), 1.0f);
    const float ay1 = fminf(fmaxf(qy1 - fy1, 0.0f), 1.0f);
    const float ax1 = fminf(fmaxf(qx1 - fx1, 0.0f), 1.0f);

    const float4* __restrict__ img4 = (const float4*)image;

    const unsigned baseA = (unsigned)(((b0 * H + (int)fy0) * W + (int)fx0) * (int)QUADS + t);
    const unsigned baseB = (unsigned)(((b1 * H + (int)fy1) * W + (int)fx1) * (int)QUADS + t);

    // 8 independent gathers — issue all before any wait
    const float4 Atl = img4[baseA];
    const float4 Atr = img4[baseA + QUADS];
    const float4 Abl = img4[baseA + ROWQ];
    const float4 Abr = img4[baseA + ROWQ + QUADS];
    const float4 Btl = img4[baseB];
    const float4 Btr = img4[baseB + QUADS];
    const float4 Bbl = img4[baseB + ROWQ];
    const float4 Bbr = img4[baseB + ROWQ + QUADS];

    const float4 r0 = bilerp4(Atl, Atr, Abl, Abr, ax0, ay0);
    const float4 r1 = bilerp4(Btl, Btr, Bbl, Bbr, ax1, ay1);

    nvec4* __restrict__ out4 = (nvec4*)out;
    const nvec4 v0 = {r0.x, r0.y, r0.z, r0.w};
    const nvec4 v1 = {r1.x, r1.y, r1.z, r1.w};
    __builtin_nontemporal_store(v0, out4 + ((unsigned)p0 * QUADS + t));
    __builtin_nontemporal_store(v1, out4 + ((unsigned)p1 * QUADS + t));
}

extern "C" void kernel_launch(void* const* d_in, const int* in_sizes, int n_in,
                              void* d_out, int out_size, void* d_ws, size_t ws_size,
                              hipStream_t stream) {
    const float* image = (const float*)d_in[0];
    const float* flow  = (const float*)d_in[1];
    float* out = (float*)d_out;

    constexpr int B = 8, H = 256, W = 256;
    const int total_threads = B * H * W * 16 / 2;  // 4,194,304
    const int block = 256;
    const int grid = total_threads / block;        // 16,384

    warp_bilinear_kernel<<<grid, block, 0, stream>>>(image, flow, out);
}